// Round 17
// baseline (186.303 us; speedup 1.0000x reference)
//
#include <hip/hip_runtime.h>
#include <hip/hip_bf16.h>
#include <cstdint>
#include <cstddef>

#define N_ROWS 8192
#define K_DIM  256
#define NP     5532
#define NC     10532
#define NCPAD  10752    // 84*128, zero-padded classes
#define IGN    5554
#define BM     128
#define BN     128
#define CT     84             // NCPAD / BN
#define NBLK   (CT * 64)      // 5376 blocks, %8==0 -> bijective XCD swizzle
#define CPX    (NBLK / 8)     // 672

using f32x4  = __attribute__((ext_vector_type(4))) float;
using bf16x8 = __attribute__((ext_vector_type(8))) short;

__device__ __forceinline__ unsigned short f2bf(float f) {
    __hip_bfloat16 h = __float2bfloat16(f);
    return __builtin_bit_cast(unsigned short, h);
}

// One-shot f32 -> bf16 conversion of X and W=[lut;cq;zero-pad] (R15-exact).
__global__ __launch_bounds__(256) void oim_convert(
    const float* __restrict__ X, const float* __restrict__ lut,
    const float* __restrict__ cq,
    unsigned short* __restrict__ Xb, unsigned short* __restrict__ Wb)
{
    const int XCH = (N_ROWS * K_DIM) / 8;   // 262144 chunks of 8 elems
    const int WCH = (NCPAD * K_DIM) / 8;    // 344064
    int c = blockIdx.x * 256 + threadIdx.x;
    if (c >= XCH + WCH) return;
    const float* src = nullptr;
    unsigned short* dst;
    if (c < XCH) {
        src = X + (size_t)c * 8;
        dst = Xb + (size_t)c * 8;
    } else {
        int wc  = c - XCH;
        int row = wc >> 5;          // 32 chunks per 256-elem row
        int off = (wc & 31) * 8;
        dst = Wb + (size_t)wc * 8;
        if (row < NP)      src = lut + (size_t)row * K_DIM + off;
        else if (row < NC) src = cq + (size_t)(row - NP) * K_DIM + off;
    }
    ushort4 h0 = {0, 0, 0, 0}, h1 = {0, 0, 0, 0};
    if (src) {
        float4 v0 = *reinterpret_cast<const float4*>(src);
        float4 v1 = *reinterpret_cast<const float4*>(src + 4);
        h0.x = f2bf(v0.x); h0.y = f2bf(v0.y); h0.z = f2bf(v0.z); h0.w = f2bf(v0.w);
        h1.x = f2bf(v1.x); h1.y = f2bf(v1.y); h1.z = f2bf(v1.z); h1.w = f2bf(v1.w);
    }
    *reinterpret_cast<ushort4*>(dst)     = h0;
    *reinterpret_cast<ushort4*>(dst + 4) = h1;
}

// 128x128 bf16 GEMM, ZERO-SYNC direct-to-register design: no LDS for A/B,
// no barriers in the K-loop, no staging. Each wave loads its own MFMA
// fragments straight from global memory:
//   av[m] <- Xb[row0+wm+m*16+(lane&15)][ (lane>>4)*8 + t*32 .. +8 ]
//   bv[n] <- Wb[col0+wn+n*16+(lane&15)][ same k ]
// Each such wave-load = 64 lanes x 16B = 16 contiguous 64B segments (zero
// overfetch, L2-served; same-block waves share rows -> L1 hits). Waves are
// fully independent -> one wave's vmcnt wait overlaps the other 3 waves'
// MFMAs on the SIMD (m114), with no barrier to serialize blocks.
// Fragment algebra and epilogue identical to R7/R15 (proven absmax 0).
__global__ __launch_bounds__(256, 4) void oim_gemm(
    const unsigned short* __restrict__ Xb, const unsigned short* __restrict__ Wb,
    const int* __restrict__ roi,
    float* __restrict__ partial, float* __restrict__ labelLogit)
{
    const int bid = blockIdx.x;
    const int L   = (bid & 7) * CPX + (bid >> 3);   // XCD-chunked, bijective
    const int ct  = L >> 6;                          // 0..83 (class tile)
    const int rt  = L & 63;                          // 0..63 (row tile)
    const int row0 = rt * BM;
    const int col0 = ct * BN;
    const int tid  = threadIdx.x;
    const int wave = tid >> 6;
    const int lane = tid & 63;
    const int wm   = (wave >> 1) * 64;
    const int wn   = (wave & 1) * 64;

    __shared__ int   lbl[BM];
    __shared__ float rs[BM][2];

    if (tid < BM) lbl[tid] = roi[row0 + tid] - 1;
    __syncthreads();     // publish lbl (only sync before the epilogue one)

    // Per-lane fragment base pointers: m/n-th frag, k-group (lane>>4)*8.
    const unsigned short* aB[4];
    const unsigned short* bB[4];
#pragma unroll
    for (int m = 0; m < 4; ++m)
        aB[m] = Xb + (size_t)(row0 + wm + m * 16 + (lane & 15)) * K_DIM
                   + (lane >> 4) * 8;
#pragma unroll
    for (int n = 0; n < 4; ++n)
        bB[n] = Wb + (size_t)(col0 + wn + n * 16 + (lane & 15)) * K_DIM
                   + (lane >> 4) * 8;

    f32x4 acc[4][4] = {};

    // K-loop: 8 steps of K=32; t*32 elems = t*64 bytes (imm offset range).
    // No barriers; compiler schedules vmcnt waits and hoists loads.
#pragma unroll
    for (int t = 0; t < 8; ++t) {
        bf16x8 av[4], bv[4];
#pragma unroll
        for (int m = 0; m < 4; ++m)
            av[m] = *reinterpret_cast<const bf16x8*>(aB[m] + t * 32);
#pragma unroll
        for (int n = 0; n < 4; ++n)
            bv[n] = *reinterpret_cast<const bf16x8*>(bB[n] + t * 32);
#pragma unroll
        for (int m = 0; m < 4; ++m)
#pragma unroll
            for (int n = 0; n < 4; ++n)
                acc[m][n] = __builtin_amdgcn_mfma_f32_16x16x32_bf16(
                    av[m], bv[n], acc[m][n], 0, 0, 0);
    }

    // ---- epilogue (R15-exact): logits*30, exp(logit-30) row-sums, label ----
    // C frag layout: col = lane&15, row = (lane>>4)*4 + reg (verified).
    // 220 zero-pad cols add ~0.4% to S -> loss bias ~4e-3 << 0.22
    // (validated empirically R5/R6/R7/R12/R15/R16).
#pragma unroll
    for (int m = 0; m < 4; ++m) {
#pragma unroll
        for (int reg = 0; reg < 4; ++reg) {
            int lrow = wm + m * 16 + (lane >> 4) * 4 + reg;
            int grow = row0 + lrow;
            int lab  = lbl[lrow];
            float s = 0.0f;
#pragma unroll
            for (int n = 0; n < 4; ++n) {
                int gcol = col0 + wn + n * 16 + (lane & 15);
                float logit = acc[m][n][reg] * 30.0f;
                s += __expf(logit - 30.0f);
                if (gcol == lab) labelLogit[grow] = logit;  // unique writer
            }
#pragma unroll
            for (int off = 1; off < 16; off <<= 1) s += __shfl_xor(s, off, 64);
            if ((lane & 15) == 0) rs[lrow][wave & 1] = s;
        }
    }
    __syncthreads();
    if (tid < BM)
        partial[(size_t)ct * N_ROWS + row0 + tid] = rs[tid][0] + rs[tid][1];
}

// Per-row nll + per-block partial sums (fixed order -> deterministic).
__global__ __launch_bounds__(256) void oim_rownll(
    const float* __restrict__ partial, const float* __restrict__ labelLogit,
    const int* __restrict__ roi, float* __restrict__ blksum)
{
    __shared__ float s1[256], s2[256];
    int tid = threadIdx.x;
    int r = blockIdx.x * 256 + tid;
    float S = 0.0f;
    for (int t = 0; t < CT; ++t) S += partial[(size_t)t * N_ROWS + r];
    float lse = 30.0f + logf(S);
    int lab = roi[r] - 1;
    bool valid = (lab != IGN);
    s1[tid] = valid ? (lse - labelLogit[r]) : 0.0f;
    s2[tid] = valid ? 1.0f : 0.0f;
    __syncthreads();
    for (int o = 128; o > 0; o >>= 1) {
        if (tid < o) { s1[tid] += s1[tid + o]; s2[tid] += s2[tid + o]; }
        __syncthreads();
    }
    if (tid == 0) {
        blksum[blockIdx.x]      = s1[0];
        blksum[32 + blockIdx.x] = s2[0];
    }
}

// Final: one wave reduces the 32 block sums.
__global__ __launch_bounds__(64) void oim_reduce(
    const float* __restrict__ blksum, float* __restrict__ out)
{
    int tid = threadIdx.x;
    float a = (tid < 32) ? blksum[tid]      : 0.0f;
    float b = (tid < 32) ? blksum[32 + tid] : 0.0f;
#pragma unroll
    for (int off = 32; off > 0; off >>= 1) {
        a += __shfl_xor(a, off, 64);
        b += __shfl_xor(b, off, 64);
    }
    if (tid == 0) out[0] = a / fmaxf(b, 1.0f);
}

extern "C" void kernel_launch(void* const* d_in, const int* in_sizes, int n_in,
                              void* d_out, int out_size, void* d_ws, size_t ws_size,
                              hipStream_t stream)
{
    const float* X   = (const float*)d_in[0];
    const int*   roi = (const int*)  d_in[1];
    const float* lut = (const float*)d_in[2];
    const float* cq  = (const float*)d_in[3];
    float* out = (float*)d_out;

    char* ws = (char*)d_ws;
    unsigned short* Xb = (unsigned short*)ws;                  // 8192*256 bf16
    unsigned short* Wb = Xb + (size_t)N_ROWS * K_DIM;          // 10752*256 bf16
    float* partial     = (float*)(Wb + (size_t)NCPAD * K_DIM); // 84*8192 f32
    float* labelLogit  = partial + (size_t)CT * N_ROWS;        // 8192
    float* blksum      = labelLogit + N_ROWS;                  // 64
    size_t need = (size_t)N_ROWS * K_DIM * 2 + (size_t)NCPAD * K_DIM * 2
                + (size_t)CT * N_ROWS * 4 + (size_t)(N_ROWS + 64) * 4;
    if (ws_size < need) return;   // refuse to run rather than corrupt memory

    const int TOT_CHUNKS = ((N_ROWS + NCPAD) * K_DIM) / 8;     // 606208
    oim_convert<<<(TOT_CHUNKS + 255) / 256, 256, 0, stream>>>(X, lut, cq, Xb, Wb);
    oim_gemm<<<NBLK, 256, 0, stream>>>(Xb, Wb, roi, partial, labelLogit);
    oim_rownll<<<N_ROWS / 256, 256, 0, stream>>>(partial, labelLogit, roi, blksum);
    oim_reduce<<<1, 64, 0, stream>>>(blksum, out);
}

// Round 18
// 86.657 us; speedup vs baseline: 2.1499x; 2.1499x over previous
//
#include <hip/hip_runtime.h>
#include <hip/hip_bf16.h>
#include <cstdint>
#include <cstddef>

#define N_ROWS 8192
#define K_DIM  256
#define NP     5532
#define NC     10532
#define NCPAD  10752    // 84*128, zero-padded classes
#define IGN    5554
#define BM     128
#define BN     128
#define BK     32
#define CT     84             // NCPAD / BN
#define NBLK   (CT * 64)      // 5376 blocks, %8==0 -> bijective XCD swizzle
#define CPX    (NBLK / 8)     // 672

using f32x4  = __attribute__((ext_vector_type(4))) float;
using bf16x8 = __attribute__((ext_vector_type(8))) short;

__device__ __forceinline__ unsigned short f2bf(float f) {
    __hip_bfloat16 h = __float2bfloat16(f);
    return __builtin_bit_cast(unsigned short, h);
}

// One-shot f32 -> bf16 conversion of X and W=[lut;cq;zero-pad] (R15-exact).
__global__ __launch_bounds__(256) void oim_convert(
    const float* __restrict__ X, const float* __restrict__ lut,
    const float* __restrict__ cq,
    unsigned short* __restrict__ Xb, unsigned short* __restrict__ Wb)
{
    const int XCH = (N_ROWS * K_DIM) / 8;   // 262144 chunks of 8 elems
    const int WCH = (NCPAD * K_DIM) / 8;    // 344064
    int c = blockIdx.x * 256 + threadIdx.x;
    if (c >= XCH + WCH) return;
    const float* src = nullptr;
    unsigned short* dst;
    if (c < XCH) {
        src = X + (size_t)c * 8;
        dst = Xb + (size_t)c * 8;
    } else {
        int wc  = c - XCH;
        int row = wc >> 5;          // 32 chunks per 256-elem row
        int off = (wc & 31) * 8;
        dst = Wb + (size_t)wc * 8;
        if (row < NP)      src = lut + (size_t)row * K_DIM + off;
        else if (row < NC) src = cq + (size_t)(row - NP) * K_DIM + off;
    }
    ushort4 h0 = {0, 0, 0, 0}, h1 = {0, 0, 0, 0};
    if (src) {
        float4 v0 = *reinterpret_cast<const float4*>(src);
        float4 v1 = *reinterpret_cast<const float4*>(src + 4);
        h0.x = f2bf(v0.x); h0.y = f2bf(v0.y); h0.z = f2bf(v0.z); h0.w = f2bf(v0.w);
        h1.x = f2bf(v1.x); h1.y = f2bf(v1.y); h1.z = f2bf(v1.z); h1.w = f2bf(v1.w);
    }
    *reinterpret_cast<ushort4*>(dst)     = h0;
    *reinterpret_cast<ushort4*>(dst + 4) = h1;
}

// 128x128 bf16 GEMM — R15-exact structure (passing, 76.4us) + ONE change:
// a prologue s_sleep stagger keyed on raw blockIdx (co-resident blocks on
// a CU are spaced ~256 apart in dispatch order). All co-resident blocks
// share the same ~1090-cyc barrier period; without stagger they convoy
// (all drain together -> ~45% dead issue slots). Sleep 0/~384/~768 cyc
// de-phases them so one block's stage-drain hides under the others'
// compute. Semantics-free; worst case costs <0.5% runtime.
// K-step (R15): {ds_read frags -> sync -> STAGE(T+1) -> MFMA -> sync}.
// LDS layout per operand (128 rows x 32 k): two rows per 128B line,
//   byte(r,g) = (r>>1)*128 + (r&1)*64 + ((g ^ ((r>>1)&3))<<4), g = k/8
// -> ds_read_b128 reads exactly 2-way bank-aliased (free, m136).
// Staged via global_load_lds w=16 (linear dest); source pre-permuted with
// inverse map r=((c>>3)<<1)|((c>>2)&1), g=(c&3)^((c>>3)&3). (R7-verified)
__global__ __launch_bounds__(256, 4) void oim_gemm(
    const unsigned short* __restrict__ Xb, const unsigned short* __restrict__ Wb,
    const int* __restrict__ roi,
    float* __restrict__ partial, float* __restrict__ labelLogit)
{
    const int bid = blockIdx.x;
    const int L   = (bid & 7) * CPX + (bid >> 3);   // XCD-chunked, bijective
    const int ct  = L >> 6;                          // 0..83 (class tile)
    const int rt  = L & 63;                          // 0..63 (row tile)
    const int row0 = rt * BM;
    const int col0 = ct * BN;
    const int tid  = threadIdx.x;
    const int wave = tid >> 6;
    const int lane = tid & 63;
    const int wm   = (wave >> 1) * 64;
    const int wn   = (wave & 1) * 64;

    __shared__ __align__(16) unsigned short As[BM * BK];   // 8 KB
    __shared__ __align__(16) unsigned short Bs[BN * BK];   // 8 KB
    __shared__ int   lbl[BM];
    __shared__ float rs[BM][2];

    if (tid < BM) lbl[tid] = roi[row0 + tid] - 1;

    // Convoy-breaking stagger: co-resident blocks (bid, bid+256, bid+512)
    // get sleep 0 / ~384 / ~768 cycles. Wave-uniform scalar branch.
    {
        int phase = (bid >> 8) % 3;
        if (phase == 1) {
            __builtin_amdgcn_s_sleep(6);
        } else if (phase == 2) {
            __builtin_amdgcn_s_sleep(6);
            __builtin_amdgcn_s_sleep(6);
        }
    }

    // Staging source pointers (pre-permuted), one per 256-chunk group.
    const unsigned short* aP[2];
    const unsigned short* bP[2];
#pragma unroll
    for (int i = 0; i < 2; ++i) {
        int c = i * 256 + tid;
        int r = ((c >> 3) << 1) | ((c >> 2) & 1);
        int g = (c & 3) ^ ((c >> 3) & 3);
        aP[i] = Xb + (size_t)(row0 + r) * K_DIM + g * 8;
        bP[i] = Wb + (size_t)(col0 + r) * K_DIM + g * 8;
    }

    // LDS read base byte-offsets (m/n add 1024; swizzle invariant under +16 rows).
    const int rA = wm + (lane & 15);
    const int rB = wn + (lane & 15);
    const int gK = lane >> 4;                        // k-chunk 0..3
    const int aOff = ((rA >> 1) << 7) + ((rA & 1) << 6)
                   + ((gK ^ ((rA >> 1) & 3)) << 4);
    const int bOff = ((rB >> 1) << 7) + ((rB & 1) << 6)
                   + ((gK ^ ((rB >> 1) & 3)) << 4);

    f32x4 acc[4][4] = {};
    bf16x8 av[4], bv[4];

    auto ldsread = [&]() {
#pragma unroll
        for (int m = 0; m < 4; ++m)
            av[m] = *reinterpret_cast<bf16x8*>(
                reinterpret_cast<char*>(As) + aOff + m * 1024);
#pragma unroll
        for (int n = 0; n < 4; ++n)
            bv[n] = *reinterpret_cast<bf16x8*>(
                reinterpret_cast<char*>(Bs) + bOff + n * 1024);
    };
    auto mfma = [&]() {
#pragma unroll
        for (int m = 0; m < 4; ++m)
#pragma unroll
            for (int n = 0; n < 4; ++n)
                acc[m][n] = __builtin_amdgcn_mfma_f32_16x16x32_bf16(
                    av[m], bv[n], acc[m][n], 0, 0, 0);
    };

#define STAGE(T)                                                              \
    do {                                                                      \
        __builtin_amdgcn_global_load_lds(                                     \
            (const __attribute__((address_space(1))) void*)aP[0],             \
            (__attribute__((address_space(3))) void*)                         \
                ((char*)As + wave * 1024), 16, (T) * 64, 0);                  \
        __builtin_amdgcn_global_load_lds(                                     \
            (const __attribute__((address_space(1))) void*)aP[1],             \
            (__attribute__((address_space(3))) void*)                         \
                ((char*)As + 4096 + wave * 1024), 16, (T) * 64, 0);           \
        __builtin_amdgcn_global_load_lds(                                     \
            (const __attribute__((address_space(1))) void*)bP[0],             \
            (__attribute__((address_space(3))) void*)                         \
                ((char*)Bs + wave * 1024), 16, (T) * 64, 0);                  \
        __builtin_amdgcn_global_load_lds(                                     \
            (const __attribute__((address_space(1))) void*)bP[1],             \
            (__attribute__((address_space(3))) void*)                         \
                ((char*)Bs + 4096 + wave * 1024), 16, (T) * 64, 0);           \
    } while (0)

#define ITER(T)                                                               \
    do {                                                                      \
        ldsread();                                                            \
        __syncthreads();   /* (a) all waves' frags in regs              */    \
        STAGE((T) + 1);    /* overwrite single buffer, latency starts   */    \
        mfma();            /* register-only, overlaps stage latency     */    \
        __syncthreads();   /* (b) vmcnt(0) drain: buffer ready for T+1  */    \
    } while (0)

    STAGE(0);
    __syncthreads();
    ITER(0); ITER(1); ITER(2); ITER(3); ITER(4); ITER(5); ITER(6);
    ldsread();
    mfma();
#undef ITER
#undef STAGE

    // ---- epilogue (R15-exact): logits*30, exp(logit-30) row-sums, label ----
    // C frag layout: col = lane&15, row = (lane>>4)*4 + reg (verified).
    // 220 zero-pad cols add ~0.4% to S -> loss bias ~4e-3 << 0.22
    // (validated empirically R5/R6/R7/R12/R15/R16).
#pragma unroll
    for (int m = 0; m < 4; ++m) {
#pragma unroll
        for (int reg = 0; reg < 4; ++reg) {
            int lrow = wm + m * 16 + (lane >> 4) * 4 + reg;
            int grow = row0 + lrow;
            int lab  = lbl[lrow];
            float s = 0.0f;
#pragma unroll
            for (int n = 0; n < 4; ++n) {
                int gcol = col0 + wn + n * 16 + (lane & 15);
                float logit = acc[m][n][reg] * 30.0f;
                s += __expf(logit - 30.0f);
                if (gcol == lab) labelLogit[grow] = logit;  // unique writer
            }
#pragma unroll
            for (int off = 1; off < 16; off <<= 1) s += __shfl_xor(s, off, 64);
            if ((lane & 15) == 0) rs[lrow][wave & 1] = s;
        }
    }
    __syncthreads();
    if (tid < BM)
        partial[(size_t)ct * N_ROWS + row0 + tid] = rs[tid][0] + rs[tid][1];
}

// Per-row nll + per-block partial sums (fixed order -> deterministic).
__global__ __launch_bounds__(256) void oim_rownll(
    const float* __restrict__ partial, const float* __restrict__ labelLogit,
    const int* __restrict__ roi, float* __restrict__ blksum)
{
    __shared__ float s1[256], s2[256];
    int tid = threadIdx.x;
    int r = blockIdx.x * 256 + tid;
    float S = 0.0f;
    for (int t = 0; t < CT; ++t) S += partial[(size_t)t * N_ROWS + r];
    float lse = 30.0f + logf(S);
    int lab = roi[r] - 1;
    bool valid = (lab != IGN);
    s1[tid] = valid ? (lse - labelLogit[r]) : 0.0f;
    s2[tid] = valid ? 1.0f : 0.0f;
    __syncthreads();
    for (int o = 128; o > 0; o >>= 1) {
        if (tid < o) { s1[tid] += s1[tid + o]; s2[tid] += s2[tid + o]; }
        __syncthreads();
    }
    if (tid == 0) {
        blksum[blockIdx.x]      = s1[0];
        blksum[32 + blockIdx.x] = s2[0];
    }
}

// Final: one wave reduces the 32 block sums.
__global__ __launch_bounds__(64) void oim_reduce(
    const float* __restrict__ blksum, float* __restrict__ out)
{
    int tid = threadIdx.x;
    float a = (tid < 32) ? blksum[tid]      : 0.0f;
    float b = (tid < 32) ? blksum[32 + tid] : 0.0f;
#pragma unroll
    for (int off = 32; off > 0; off >>= 1) {
        a += __shfl_xor(a, off, 64);
        b += __shfl_xor(b, off, 64);
    }
    if (tid == 0) out[0] = a / fmaxf(b, 1.0f);
}

extern "C" void kernel_launch(void* const* d_in, const int* in_sizes, int n_in,
                              void* d_out, int out_size, void* d_ws, size_t ws_size,
                              hipStream_t stream)
{
    const float* X   = (const float*)d_in[0];
    const int*   roi = (const int*)  d_in[1];
    const float* lut = (const float*)d_in[2];
    const float* cq  = (const float*)d_in[3];
    float* out = (float*)d_out;

    char* ws = (char*)d_ws;
    unsigned short* Xb = (unsigned short*)ws;                  // 8192*256 bf16
    unsigned short* Wb = Xb + (size_t)N_ROWS * K_DIM;          // 10752*256 bf16
    float* partial     = (float*)(Wb + (size_t)NCPAD * K_DIM); // 84*8192 f32
    float* labelLogit  = partial + (size_t)CT * N_ROWS;        // 8192
    float* blksum      = labelLogit + N_ROWS;                  // 64
    size_t need = (size_t)N_ROWS * K_DIM * 2 + (size_t)NCPAD * K_DIM * 2
                + (size_t)CT * N_ROWS * 4 + (size_t)(N_ROWS + 64) * 4;
    if (ws_size < need) return;   // refuse to run rather than corrupt memory

    const int TOT_CHUNKS = ((N_ROWS + NCPAD) * K_DIM) / 8;     // 606208
    oim_convert<<<(TOT_CHUNKS + 255) / 256, 256, 0, stream>>>(X, lut, cq, Xb, Wb);
    oim_gemm<<<NBLK, 256, 0, stream>>>(Xb, Wb, roi, partial, labelLogit);
    oim_rownll<<<N_ROWS / 256, 256, 0, stream>>>(partial, labelLogit, roi, blksum);
    oim_reduce<<<1, 64, 0, stream>>>(blksum, out);
}

// Round 19
// 72.603 us; speedup vs baseline: 2.5661x; 1.1936x over previous
//
#include <hip/hip_runtime.h>
#include <hip/hip_bf16.h>
#include <cstdint>
#include <cstddef>

#define N_ROWS 8192
#define K_DIM  256
#define NP     5532
#define NC     10532
#define NCPAD  10752    // 84*128, zero-padded classes
#define IGN    5554
#define BM     128
#define BN     128
#define BK     64              // fp8: 64 k-elems = 64 B/row per step
#define CT     84              // NCPAD / BN
#define NBLK   (CT * 64)       // 5376 blocks, %8==0 -> bijective XCD swizzle
#define CPX    (NBLK / 8)      // 672

using f32x4 = __attribute__((ext_vector_type(4))) float;

// One-shot f32 -> fp8 e4m3 (OCP, HW cvt) of X and W=[lut;cq;zero-pad].
__global__ __launch_bounds__(256) void oim_convert(
    const float* __restrict__ X, const float* __restrict__ lut,
    const float* __restrict__ cq,
    unsigned char* __restrict__ Xb, unsigned char* __restrict__ Wb)
{
    const int XCH = (N_ROWS * K_DIM) / 8;   // 262144 chunks of 8 elems
    const int WCH = (NCPAD * K_DIM) / 8;    // 344064
    int c = blockIdx.x * 256 + threadIdx.x;
    if (c >= XCH + WCH) return;
    const float* src = nullptr;
    unsigned char* dst;
    if (c < XCH) {
        src = X + (size_t)c * 8;
        dst = Xb + (size_t)c * 8;
    } else {
        int wc  = c - XCH;
        int row = wc >> 5;          // 32 chunks per 256-elem row
        int off = (wc & 31) * 8;
        dst = Wb + (size_t)wc * 8;
        if (row < NP)      src = lut + (size_t)row * K_DIM + off;
        else if (row < NC) src = cq + (size_t)(row - NP) * K_DIM + off;
    }
    unsigned int lo = 0, hi = 0;
    if (src) {
        float4 v0 = *reinterpret_cast<const float4*>(src);
        float4 v1 = *reinterpret_cast<const float4*>(src + 4);
        lo = __builtin_amdgcn_cvt_pk_fp8_f32(v0.x, v0.y, 0,  false);
        lo = __builtin_amdgcn_cvt_pk_fp8_f32(v0.z, v0.w, lo, true);
        hi = __builtin_amdgcn_cvt_pk_fp8_f32(v1.x, v1.y, 0,  false);
        hi = __builtin_amdgcn_cvt_pk_fp8_f32(v1.z, v1.w, hi, true);
    }
    uint2 o; o.x = lo; o.y = hi;
    *reinterpret_cast<uint2*>(dst) = o;     // dst is 8B-aligned (c*8)
}

// 128x128 fp8 GEMM, BK=64: staging geometry BYTE-IDENTICAL to the proven
// R7/R15 path (rows of 64B, 512 chunks/operand, chunk c -> r=((c>>3)<<1)|
// ((c>>2)&1), gq=(c&3)^((c>>3)&3), 16B at row*256+gq*16, imm offset T*64,
// 4 loads/thread/step, 18KB LDS, plain __syncthreads) — but 4 K-steps
// instead of 8, halving the dominant per-step drain count.
// Fragments: mfma_f32_16x16x32_fp8_fp8 (A/B = 8 fp8/lane = one b64 read;
// row = lane&15, k = (lane>>4)*8 + j, +32 for ksub1). LDS read:
//   addr(r, gg) = (r>>1)*128 + (r&1)*64 + (((gg>>1)^((r>>1)&3))<<4)
//                 + (gg&1)*8,   gg = ksub*4 + (lane>>4)
// (write/read consistency hand-verified on chunks c=0,2,4,8).
// K-step order = R15 (proven): {ds_read -> sync -> STAGE(T+1) -> MFMA -> sync}.
__global__ __launch_bounds__(256, 4) void oim_gemm(
    const unsigned char* __restrict__ Xb, const unsigned char* __restrict__ Wb,
    const int* __restrict__ roi,
    float* __restrict__ partial, float* __restrict__ labelLogit)
{
    const int bid = blockIdx.x;
    const int L   = (bid & 7) * CPX + (bid >> 3);   // XCD-chunked, bijective
    const int ct  = L >> 6;                          // 0..83 (class tile)
    const int rt  = L & 63;                          // 0..63 (row tile)
    const int row0 = rt * BM;
    const int col0 = ct * BN;
    const int tid  = threadIdx.x;
    const int wave = tid >> 6;
    const int lane = tid & 63;
    const int wm   = (wave >> 1) * 64;
    const int wn   = (wave & 1) * 64;

    __shared__ __align__(16) unsigned char As[BM * BK];   // 8 KB
    __shared__ __align__(16) unsigned char Bs[BN * BK];   // 8 KB
    __shared__ int   lbl[BM];
    __shared__ float rs[BM][2];

    if (tid < BM) lbl[tid] = roi[row0 + tid] - 1;

    // Staging source pointers (pre-permuted), one per 256-chunk group.
    const unsigned char* aP[2];
    const unsigned char* bP[2];
#pragma unroll
    for (int i = 0; i < 2; ++i) {
        int c  = i * 256 + tid;
        int r  = ((c >> 3) << 1) | ((c >> 2) & 1);
        int gq = (c & 3) ^ ((c >> 3) & 3);
        aP[i] = Xb + (size_t)(row0 + r) * K_DIM + gq * 16;
        bP[i] = Wb + (size_t)(col0 + r) * K_DIM + gq * 16;
    }

    // Fragment read offsets (b64 each; m/n add 1024 — swizzle invariant).
    const int rA = wm + (lane & 15);
    const int rB = wn + (lane & 15);
    const int gs = lane >> 4;                        // 0..3
    const int swA = (rA >> 1) & 3, swB = (rB >> 1) & 3;
    const int aBse = ((rA >> 1) << 7) + ((rA & 1) << 6) + ((gs & 1) << 3);
    const int bBse = ((rB >> 1) << 7) + ((rB & 1) << 6) + ((gs & 1) << 3);
    const int aO0 = aBse + ((((gs >> 1))     ^ swA) << 4);   // ksub 0
    const int aO1 = aBse + ((((gs >> 1) + 2) ^ swA) << 4);   // ksub 1
    const int bO0 = bBse + ((((gs >> 1))     ^ swB) << 4);
    const int bO1 = bBse + ((((gs >> 1) + 2) ^ swB) << 4);

    f32x4 acc[4][4] = {};
    long av0[4], av1[4], bv0[4], bv1[4];

    auto ldsread = [&]() {
#pragma unroll
        for (int m = 0; m < 4; ++m) {
            av0[m] = *reinterpret_cast<const long*>(As + aO0 + m * 1024);
            av1[m] = *reinterpret_cast<const long*>(As + aO1 + m * 1024);
        }
#pragma unroll
        for (int n = 0; n < 4; ++n) {
            bv0[n] = *reinterpret_cast<const long*>(Bs + bO0 + n * 1024);
            bv1[n] = *reinterpret_cast<const long*>(Bs + bO1 + n * 1024);
        }
    };
    auto mfma = [&]() {
#pragma unroll
        for (int m = 0; m < 4; ++m)
#pragma unroll
            for (int n = 0; n < 4; ++n)
                acc[m][n] = __builtin_amdgcn_mfma_f32_16x16x32_fp8_fp8(
                    av0[m], bv0[n], acc[m][n], 0, 0, 0);
#pragma unroll
        for (int m = 0; m < 4; ++m)
#pragma unroll
            for (int n = 0; n < 4; ++n)
                acc[m][n] = __builtin_amdgcn_mfma_f32_16x16x32_fp8_fp8(
                    av1[m], bv1[n], acc[m][n], 0, 0, 0);
    };

#define STAGE(T)                                                              \
    do {                                                                      \
        __builtin_amdgcn_global_load_lds(                                     \
            (const __attribute__((address_space(1))) void*)aP[0],             \
            (__attribute__((address_space(3))) void*)                         \
                ((char*)As + wave * 1024), 16, (T) * 64, 0);                  \
        __builtin_amdgcn_global_load_lds(                                     \
            (const __attribute__((address_space(1))) void*)aP[1],             \
            (__attribute__((address_space(3))) void*)                         \
                ((char*)As + 4096 + wave * 1024), 16, (T) * 64, 0);           \
        __builtin_amdgcn_global_load_lds(                                     \
            (const __attribute__((address_space(1))) void*)bP[0],             \
            (__attribute__((address_space(3))) void*)                         \
                ((char*)Bs + wave * 1024), 16, (T) * 64, 0);                  \
        __builtin_amdgcn_global_load_lds(                                     \
            (const __attribute__((address_space(1))) void*)bP[1],             \
            (__attribute__((address_space(3))) void*)                         \
                ((char*)Bs + 4096 + wave * 1024), 16, (T) * 64, 0);           \
    } while (0)

#define ITER(T)                                                               \
    do {                                                                      \
        ldsread();                                                            \
        __syncthreads();   /* (a) all waves' frags in regs              */    \
        STAGE((T) + 1);    /* overwrite single buffer, latency starts   */    \
        mfma();            /* register-only, overlaps stage latency     */    \
        __syncthreads();   /* (b) vmcnt(0) drain: buffer ready for T+1  */    \
    } while (0)

    STAGE(0);
    __syncthreads();
    ITER(0); ITER(1); ITER(2);
    ldsread();
    mfma();
#undef ITER
#undef STAGE

    // ---- epilogue (R15-exact): logits*30, exp(logit-30) row-sums, label ----
    // C frag layout: col = lane&15, row = (lane>>4)*4 + reg (dtype-indep).
    // 220 zero-pad cols add ~0.4% to S -> loss bias ~4e-3 << 0.22.
#pragma unroll
    for (int m = 0; m < 4; ++m) {
#pragma unroll
        for (int reg = 0; reg < 4; ++reg) {
            int lrow = wm + m * 16 + (lane >> 4) * 4 + reg;
            int grow = row0 + lrow;
            int lab  = lbl[lrow];
            float s = 0.0f;
#pragma unroll
            for (int n = 0; n < 4; ++n) {
                int gcol = col0 + wn + n * 16 + (lane & 15);
                float logit = acc[m][n][reg] * 30.0f;
                s += __expf(logit - 30.0f);
                if (gcol == lab) labelLogit[grow] = logit;  // unique writer
            }
#pragma unroll
            for (int off = 1; off < 16; off <<= 1) s += __shfl_xor(s, off, 64);
            if ((lane & 15) == 0) rs[lrow][wave & 1] = s;
        }
    }
    __syncthreads();
    if (tid < BM)
        partial[(size_t)ct * N_ROWS + row0 + tid] = rs[tid][0] + rs[tid][1];
}

// Per-row nll + per-block partial sums (fixed order -> deterministic).
__global__ __launch_bounds__(256) void oim_rownll(
    const float* __restrict__ partial, const float* __restrict__ labelLogit,
    const int* __restrict__ roi, float* __restrict__ blksum)
{
    __shared__ float s1[256], s2[256];
    int tid = threadIdx.x;
    int r = blockIdx.x * 256 + tid;
    float S = 0.0f;
    for (int t = 0; t < CT; ++t) S += partial[(size_t)t * N_ROWS + r];
    float lse = 30.0f + logf(S);
    int lab = roi[r] - 1;
    bool valid = (lab != IGN);
    s1[tid] = valid ? (lse - labelLogit[r]) : 0.0f;
    s2[tid] = valid ? 1.0f : 0.0f;
    __syncthreads();
    for (int o = 128; o > 0; o >>= 1) {
        if (tid < o) { s1[tid] += s1[tid + o]; s2[tid] += s2[tid + o]; }
        __syncthreads();
    }
    if (tid == 0) {
        blksum[blockIdx.x]      = s1[0];
        blksum[32 + blockIdx.x] = s2[0];
    }
}

// Final: one wave reduces the 32 block sums.
__global__ __launch_bounds__(64) void oim_reduce(
    const float* __restrict__ blksum, float* __restrict__ out)
{
    int tid = threadIdx.x;
    float a = (tid < 32) ? blksum[tid]      : 0.0f;
    float b = (tid < 32) ? blksum[32 + tid] : 0.0f;
#pragma unroll
    for (int off = 32; off > 0; off >>= 1) {
        a += __shfl_xor(a, off, 64);
        b += __shfl_xor(b, off, 64);
    }
    if (tid == 0) out[0] = a / fmaxf(b, 1.0f);
}

extern "C" void kernel_launch(void* const* d_in, const int* in_sizes, int n_in,
                              void* d_out, int out_size, void* d_ws, size_t ws_size,
                              hipStream_t stream)
{
    const float* X   = (const float*)d_in[0];
    const int*   roi = (const int*)  d_in[1];
    const float* lut = (const float*)d_in[2];
    const float* cq  = (const float*)d_in[3];
    float* out = (float*)d_out;

    char* ws = (char*)d_ws;
    unsigned char* Xb = (unsigned char*)ws;                  // 8192*256 fp8
    unsigned char* Wb = Xb + (size_t)N_ROWS * K_DIM;         // 10752*256 fp8
    float* partial    = (float*)(Wb + (size_t)NCPAD * K_DIM);// 84*8192 f32
    float* labelLogit = partial + (size_t)CT * N_ROWS;       // 8192
    float* blksum     = labelLogit + N_ROWS;                 // 64
    size_t need = (size_t)N_ROWS * K_DIM + (size_t)NCPAD * K_DIM
                + (size_t)CT * N_ROWS * 4 + (size_t)(N_ROWS + 64) * 4;
    if (ws_size < need) return;   // refuse to run rather than corrupt memory

    const int TOT_CHUNKS = ((N_ROWS + NCPAD) * K_DIM) / 8;   // 606208
    oim_convert<<<(TOT_CHUNKS + 255) / 256, 256, 0, stream>>>(X, lut, cq, Xb, Wb);
    oim_gemm<<<NBLK, 256, 0, stream>>>(Xb, Wb, roi, partial, labelLogit);
    oim_rownll<<<N_ROWS / 256, 256, 0, stream>>>(partial, labelLogit, roi, blksum);
    oim_reduce<<<1, 64, 0, stream>>>(blksum, out);
}

// Round 20
// 65.241 us; speedup vs baseline: 2.8556x; 1.1128x over previous
//
#include <hip/hip_runtime.h>
#include <hip/hip_bf16.h>
#include <cstdint>
#include <cstddef>

#define N_ROWS 8192
#define K_DIM  256
#define NP     5532
#define NC     10532
#define NCPAD  10752    // 84*128, zero-padded classes
#define IGN    5554
#define BM     128
#define BN     128
#define BK     64              // fp8: 64 k-elems = 64 B/row per step
#define CT     84              // NCPAD / BN
#define NBLK   (CT * 64)       // 5376 blocks, %8==0 -> bijective XCD swizzle
#define CPX    (NBLK / 8)      // 672

using f32x4 = __attribute__((ext_vector_type(4))) float;
using i64x2 = __attribute__((ext_vector_type(2))) long;

// One-shot f32 -> fp8 e4m3 with PAIR-PACKED k-layout: within each 64-byte
// k-block of a row, byte position g*16+sub*8 holds k = sub*32 + g*8 .. +8.
// So the 16B unit g of a k-block contains exactly lane-group g's two MFMA
// fragments (ksub0, ksub1) -> single ds_read_b128 per fragment pair.
__global__ __launch_bounds__(256) void oim_convert(
    const float* __restrict__ X, const float* __restrict__ lut,
    const float* __restrict__ cq,
    unsigned char* __restrict__ Xb, unsigned char* __restrict__ Wb)
{
    const int XCH = (N_ROWS * K_DIM) / 8;   // 262144 chunks of 8 elems
    const int WCH = (NCPAD * K_DIM) / 8;    // 344064
    int c = blockIdx.x * 256 + threadIdx.x;
    if (c >= XCH + WCH) return;
    const float* src = nullptr;
    unsigned char* dst;
    int row, qg;   // row and 8-elem group index within row (0..31)
    if (c < XCH) {
        row = c >> 5; qg = c & 31;
        src = X + (size_t)c * 8;
        dst = Xb + (size_t)row * K_DIM;
    } else {
        int wc = c - XCH;
        row = wc >> 5; qg = wc & 31;
        dst = Wb + (size_t)row * K_DIM;
        if (row < NP)      src = lut + (size_t)row * K_DIM + qg * 8;
        else if (row < NC) src = cq + (size_t)(row - NP) * K_DIM + qg * 8;
    }
    // pair-packed offset: kblk = qg>>3, g = qg&3, sub = (qg>>2)&1
    dst += (qg >> 3) * 64 + (qg & 3) * 16 + ((qg >> 2) & 1) * 8;
    unsigned int lo = 0, hi = 0;
    if (src) {
        float4 v0 = *reinterpret_cast<const float4*>(src);
        float4 v1 = *reinterpret_cast<const float4*>(src + 4);
        lo = __builtin_amdgcn_cvt_pk_fp8_f32(v0.x, v0.y, 0,  false);
        lo = __builtin_amdgcn_cvt_pk_fp8_f32(v0.z, v0.w, lo, true);
        hi = __builtin_amdgcn_cvt_pk_fp8_f32(v1.x, v1.y, 0,  false);
        hi = __builtin_amdgcn_cvt_pk_fp8_f32(v1.z, v1.w, hi, true);
    }
    uint2 o; o.x = lo; o.y = hi;
    *reinterpret_cast<uint2*>(dst) = o;     // dst is 8B-aligned
}

// 128x128 fp8 GEMM, BK=64, 4 K-steps — staging geometry byte-identical to
// the R7/R15/R19 proven path (512 16B chunks/operand, chunk c ->
// r=((c>>3)<<1)|((c>>2)&1), gq=(c&3)^((c>>3)&3), src row*256+gq*16,
// imm offset T*64, 18KB LDS, plain __syncthreads 2-barrier K-step).
// With pair-packed global layout, each fragment pair is ONE ds_read_b128
// at the R7 bf16 offset formula (2-way bank alias = free, m136) — fixes
// R19's 5.5M ds_read_b64 bank conflicts and halves ds_read count.
__global__ __launch_bounds__(256, 4) void oim_gemm(
    const unsigned char* __restrict__ Xb, const unsigned char* __restrict__ Wb,
    const int* __restrict__ roi,
    float* __restrict__ partial, float* __restrict__ labelLogit)
{
    const int bid = blockIdx.x;
    const int L   = (bid & 7) * CPX + (bid >> 3);   // XCD-chunked, bijective
    const int ct  = L >> 6;                          // 0..83 (class tile)
    const int rt  = L & 63;                          // 0..63 (row tile)
    const int row0 = rt * BM;
    const int col0 = ct * BN;
    const int tid  = threadIdx.x;
    const int wave = tid >> 6;
    const int lane = tid & 63;
    const int wm   = (wave >> 1) * 64;
    const int wn   = (wave & 1) * 64;

    __shared__ __align__(16) unsigned char As[BM * BK];   // 8 KB
    __shared__ __align__(16) unsigned char Bs[BN * BK];   // 8 KB
    __shared__ int   lbl[BM];
    __shared__ float rs[BM][2];

    if (tid < BM) lbl[tid] = roi[row0 + tid] - 1;

    // Staging source pointers (pre-permuted), one per 256-chunk group.
    const unsigned char* aP[2];
    const unsigned char* bP[2];
#pragma unroll
    for (int i = 0; i < 2; ++i) {
        int c  = i * 256 + tid;
        int r  = ((c >> 3) << 1) | ((c >> 2) & 1);
        int gq = (c & 3) ^ ((c >> 3) & 3);
        aP[i] = Xb + (size_t)(row0 + r) * K_DIM + gq * 16;
        bP[i] = Wb + (size_t)(col0 + r) * K_DIM + gq * 16;
    }

    // Fragment read offsets — R7 bf16 formula (16B units), m/n add 1024.
    const int rA = wm + (lane & 15);
    const int rB = wn + (lane & 15);
    const int gK = lane >> 4;                        // k-group 0..3
    const int aOff = ((rA >> 1) << 7) + ((rA & 1) << 6)
                   + ((gK ^ ((rA >> 1) & 3)) << 4);
    const int bOff = ((rB >> 1) << 7) + ((rB & 1) << 6)
                   + ((gK ^ ((rB >> 1) & 3)) << 4);

    f32x4 acc[4][4] = {};
    long av0[4], av1[4], bv0[4], bv1[4];

    auto ldsread = [&]() {
#pragma unroll
        for (int m = 0; m < 4; ++m) {
            i64x2 v = *reinterpret_cast<const i64x2*>(As + aOff + m * 1024);
            av0[m] = v.x; av1[m] = v.y;     // ksub0 | ksub1 (pair-packed)
        }
#pragma unroll
        for (int n = 0; n < 4; ++n) {
            i64x2 v = *reinterpret_cast<const i64x2*>(Bs + bOff + n * 1024);
            bv0[n] = v.x; bv1[n] = v.y;
        }
    };
    auto mfma = [&]() {
#pragma unroll
        for (int m = 0; m < 4; ++m)
#pragma unroll
            for (int n = 0; n < 4; ++n)
                acc[m][n] = __builtin_amdgcn_mfma_f32_16x16x32_fp8_fp8(
                    av0[m], bv0[n], acc[m][n], 0, 0, 0);
#pragma unroll
        for (int m = 0; m < 4; ++m)
#pragma unroll
            for (int n = 0; n < 4; ++n)
                acc[m][n] = __builtin_amdgcn_mfma_f32_16x16x32_fp8_fp8(
                    av1[m], bv1[n], acc[m][n], 0, 0, 0);
    };

#define STAGE(T)                                                              \
    do {                                                                      \
        __builtin_amdgcn_global_load_lds(                                     \
            (const __attribute__((address_space(1))) void*)aP[0],             \
            (__attribute__((address_space(3))) void*)                         \
                ((char*)As + wave * 1024), 16, (T) * 64, 0);                  \
        __builtin_amdgcn_global_load_lds(                                     \
            (const __attribute__((address_space(1))) void*)aP[1],             \
            (__attribute__((address_space(3))) void*)                         \
                ((char*)As + 4096 + wave * 1024), 16, (T) * 64, 0);           \
        __builtin_amdgcn_global_load_lds(                                     \
            (const __attribute__((address_space(1))) void*)bP[0],             \
            (__attribute__((address_space(3))) void*)                         \
                ((char*)Bs + wave * 1024), 16, (T) * 64, 0);                  \
        __builtin_amdgcn_global_load_lds(                                     \
            (const __attribute__((address_space(1))) void*)bP[1],             \
            (__attribute__((address_space(3))) void*)                         \
                ((char*)Bs + 4096 + wave * 1024), 16, (T) * 64, 0);           \
    } while (0)

#define ITER(T)                                                               \
    do {                                                                      \
        ldsread();                                                            \
        __syncthreads();   /* (a) all waves' frags in regs              */    \
        STAGE((T) + 1);    /* overwrite single buffer, latency starts   */    \
        mfma();            /* register-only, overlaps stage latency     */    \
        __syncthreads();   /* (b) vmcnt(0) drain: buffer ready for T+1  */    \
    } while (0)

    STAGE(0);
    __syncthreads();
    ITER(0); ITER(1); ITER(2);
    ldsread();
    mfma();
#undef ITER
#undef STAGE

    // ---- epilogue (R15-exact): logits*30, exp(logit-30) row-sums, label ----
    // C frag layout: col = lane&15, row = (lane>>4)*4 + reg (dtype-indep).
    // 220 zero-pad cols add ~0.4% to S -> loss bias ~4e-3 << 0.22.
#pragma unroll
    for (int m = 0; m < 4; ++m) {
#pragma unroll
        for (int reg = 0; reg < 4; ++reg) {
            int lrow = wm + m * 16 + (lane >> 4) * 4 + reg;
            int grow = row0 + lrow;
            int lab  = lbl[lrow];
            float s = 0.0f;
#pragma unroll
            for (int n = 0; n < 4; ++n) {
                int gcol = col0 + wn + n * 16 + (lane & 15);
                float logit = acc[m][n][reg] * 30.0f;
                s += __expf(logit - 30.0f);
                if (gcol == lab) labelLogit[grow] = logit;  // unique writer
            }
#pragma unroll
            for (int off = 1; off < 16; off <<= 1) s += __shfl_xor(s, off, 64);
            if ((lane & 15) == 0) rs[lrow][wave & 1] = s;
        }
    }
    __syncthreads();
    if (tid < BM)
        partial[(size_t)ct * N_ROWS + row0 + tid] = rs[tid][0] + rs[tid][1];
}

// Per-row nll + per-block partial sums (fixed order -> deterministic).
__global__ __launch_bounds__(256) void oim_rownll(
    const float* __restrict__ partial, const float* __restrict__ labelLogit,
    const int* __restrict__ roi, float* __restrict__ blksum)
{
    __shared__ float s1[256], s2[256];
    int tid = threadIdx.x;
    int r = blockIdx.x * 256 + tid;
    float S = 0.0f;
    for (int t = 0; t < CT; ++t) S += partial[(size_t)t * N_ROWS + r];
    float lse = 30.0f + logf(S);
    int lab = roi[r] - 1;
    bool valid = (lab != IGN);
    s1[tid] = valid ? (lse - labelLogit[r]) : 0.0f;
    s2[tid] = valid ? 1.0f : 0.0f;
    __syncthreads();
    for (int o = 128; o > 0; o >>= 1) {
        if (tid < o) { s1[tid] += s1[tid + o]; s2[tid] += s2[tid + o]; }
        __syncthreads();
    }
    if (tid == 0) {
        blksum[blockIdx.x]      = s1[0];
        blksum[32 + blockIdx.x] = s2[0];
    }
}

// Final: one wave reduces the 32 block sums.
__global__ __launch_bounds__(64) void oim_reduce(
    const float* __restrict__ blksum, float* __restrict__ out)
{
    int tid = threadIdx.x;
    float a = (tid < 32) ? blksum[tid]      : 0.0f;
    float b = (tid < 32) ? blksum[32 + tid] : 0.0f;
#pragma unroll
    for (int off = 32; off > 0; off >>= 1) {
        a += __shfl_xor(a, off, 64);
        b += __shfl_xor(b, off, 64);
    }
    if (tid == 0) out[0] = a / fmaxf(b, 1.0f);
}

extern "C" void kernel_launch(void* const* d_in, const int* in_sizes, int n_in,
                              void* d_out, int out_size, void* d_ws, size_t ws_size,
                              hipStream_t stream)
{
    const float* X   = (const float*)d_in[0];
    const int*   roi = (const int*)  d_in[1];
    const float* lut = (const float*)d_in[2];
    const float* cq  = (const float*)d_in[3];
    float* out = (float*)d_out;

    char* ws = (char*)d_ws;
    unsigned char* Xb = (unsigned char*)ws;                  // 8192*256 fp8
    unsigned char* Wb = Xb + (size_t)N_ROWS * K_DIM;         // 10752*256 fp8
    float* partial    = (float*)(Wb + (size_t)NCPAD * K_DIM);// 84*8192 f32
    float* labelLogit = partial + (size_t)CT * N_ROWS;       // 8192
    float* blksum     = labelLogit + N_ROWS;                 // 64
    size_t need = (size_t)N_ROWS * K_DIM + (size_t)NCPAD * K_DIM
                + (size_t)CT * N_ROWS * 4 + (size_t)(N_ROWS + 64) * 4;
    if (ws_size < need) return;   // refuse to run rather than corrupt memory

    const int TOT_CHUNKS = ((N_ROWS + NCPAD) * K_DIM) / 8;   // 606208
    oim_convert<<<(TOT_CHUNKS + 255) / 256, 256, 0, stream>>>(X, lut, cq, Xb, Wb);
    oim_gemm<<<NBLK, 256, 0, stream>>>(Xb, Wb, roi, partial, labelLogit);
    oim_rownll<<<N_ROWS / 256, 256, 0, stream>>>(partial, labelLogit, roi, blksum);
    oim_reduce<<<1, 64, 0, stream>>>(blksum, out);
}

// Round 21
// 64.178 us; speedup vs baseline: 2.9029x; 1.0166x over previous
//
#include <hip/hip_runtime.h>
#include <hip/hip_bf16.h>
#include <cstdint>
#include <cstddef>

#define N_ROWS 8192
#define K_DIM  256
#define NP     5532
#define NC     10532
#define NCPAD  10752    // 84*128, zero-padded classes
#define IGN    5554
#define BM     128
#define BN     128
#define BK     128             // fp8: 128 k-elems = 128 B/row per step
#define CT     84              // NCPAD / BN
#define NBLK   (CT * 64)       // 5376 blocks, %8==0 -> bijective XCD swizzle
#define CPX    (NBLK / 8)      // 672

using f32x4 = __attribute__((ext_vector_type(4))) float;
using i64x2 = __attribute__((ext_vector_type(2))) long;

// One-shot f32 -> fp8 e4m3, PAIR-PACKED k-layout (byte-identical to R20):
// within each 64B k-block of a row, byte g*16+sub*8 holds k = sub*32+g*8..+8,
// so 16B unit (k/64)*4+g holds lane-group g's (ksub0,ksub1) fragment pair.
__global__ __launch_bounds__(256) void oim_convert(
    const float* __restrict__ X, const float* __restrict__ lut,
    const float* __restrict__ cq,
    unsigned char* __restrict__ Xb, unsigned char* __restrict__ Wb)
{
    const int XCH = (N_ROWS * K_DIM) / 8;   // 262144 chunks of 8 elems
    const int WCH = (NCPAD * K_DIM) / 8;    // 344064
    int c = blockIdx.x * 256 + threadIdx.x;
    if (c >= XCH + WCH) return;
    const float* src = nullptr;
    unsigned char* dst;
    int row, qg;   // row and 8-elem group index within row (0..31)
    if (c < XCH) {
        row = c >> 5; qg = c & 31;
        src = X + (size_t)c * 8;
        dst = Xb + (size_t)row * K_DIM;
    } else {
        int wc = c - XCH;
        row = wc >> 5; qg = wc & 31;
        dst = Wb + (size_t)row * K_DIM;
        if (row < NP)      src = lut + (size_t)row * K_DIM + qg * 8;
        else if (row < NC) src = cq + (size_t)(row - NP) * K_DIM + qg * 8;
    }
    dst += (qg >> 3) * 64 + (qg & 3) * 16 + ((qg >> 2) & 1) * 8;
    unsigned int lo = 0, hi = 0;
    if (src) {
        float4 v0 = *reinterpret_cast<const float4*>(src);
        float4 v1 = *reinterpret_cast<const float4*>(src + 4);
        lo = __builtin_amdgcn_cvt_pk_fp8_f32(v0.x, v0.y, 0,  false);
        lo = __builtin_amdgcn_cvt_pk_fp8_f32(v0.z, v0.w, lo, true);
        hi = __builtin_amdgcn_cvt_pk_fp8_f32(v1.x, v1.y, 0,  false);
        hi = __builtin_amdgcn_cvt_pk_fp8_f32(v1.z, v1.w, hi, true);
    }
    uint2 o; o.x = lo; o.y = hi;
    *reinterpret_cast<uint2*>(dst) = o;
}

// 128x128 fp8 GEMM, BK=128 -> 2 K-steps, 2 exposed drains (was 4 at R20).
// kb-split K-step keeps register pressure at R20's level while all LDS
// reads complete before the buffer overwrite (R15-proven discipline):
//   {read kb0; mfma kb0; read kb1; sync(a); STAGE(next); mfma kb1; sync(b)}
// LDS: rows of 128B (8 x 16B units), XOR swizzle u_lds = u_glob ^ (r&7)
// -> unit index determines the bank set (r*128 = 0 mod 128B), 16 lanes
// land on 8 units = 2-way alias = free (m136). Staging via global_load_lds
// w=16, linear dest chunk c -> (r=c>>3, u=c&7), source pre-permuted:
//   src = row*256 + t*128 + ((u ^ (r&7))<<4)   (hand-verified c=9,45)
__global__ __launch_bounds__(256, 3) void oim_gemm(
    const unsigned char* __restrict__ Xb, const unsigned char* __restrict__ Wb,
    const int* __restrict__ roi,
    float* __restrict__ partial, float* __restrict__ labelLogit)
{
    const int bid = blockIdx.x;
    const int L   = (bid & 7) * CPX + (bid >> 3);   // XCD-chunked, bijective
    const int ct  = L >> 6;                          // 0..83 (class tile)
    const int rt  = L & 63;                          // 0..63 (row tile)
    const int row0 = rt * BM;
    const int col0 = ct * BN;
    const int tid  = threadIdx.x;
    const int wave = tid >> 6;
    const int lane = tid & 63;
    const int wm   = (wave >> 1) * 64;
    const int wn   = (wave & 1) * 64;

    __shared__ __align__(16) unsigned char As[BM * BK];   // 16 KB
    __shared__ __align__(16) unsigned char Bs[BN * BK];   // 16 KB
    __shared__ int   lbl[BM];
    __shared__ float rs[BM][2];

    if (tid < BM) lbl[tid] = roi[row0 + tid] - 1;

    // Staging source pointers (pre-permuted), 4 chunk-groups per operand.
    const unsigned char* aP[4];
    const unsigned char* bP[4];
#pragma unroll
    for (int i = 0; i < 4; ++i) {
        int c = i * 256 + tid;
        int r = c >> 3;
        int u = c & 7;
        int s = ((u ^ (r & 7)) << 4);
        aP[i] = Xb + (size_t)(row0 + r) * K_DIM + s;
        bP[i] = Wb + (size_t)(col0 + r) * K_DIM + s;
    }

    // Fragment read offsets per kb (m/n add 2048; swizzle invariant +16 rows).
    const int rA = wm + (lane & 15);
    const int rB = wn + (lane & 15);
    const int gs = lane >> 4;                        // k-group 0..3
    int aO[2], bO[2];
#pragma unroll
    for (int kb = 0; kb < 2; ++kb) {
        aO[kb] = rA * 128 + (((kb * 4 + gs) ^ (rA & 7)) << 4);
        bO[kb] = rB * 128 + (((kb * 4 + gs) ^ (rB & 7)) << 4);
    }

    f32x4 acc[4][4] = {};
    long xa0[4], xa1[4], xb0[4], xb1[4];

    auto readfrag = [&](int kb) {
#pragma unroll
        for (int m = 0; m < 4; ++m) {
            i64x2 v = *reinterpret_cast<const i64x2*>(As + aO[kb] + m * 2048);
            xa0[m] = v.x; xa1[m] = v.y;     // ksub0 | ksub1 (pair-packed)
        }
#pragma unroll
        for (int n = 0; n < 4; ++n) {
            i64x2 v = *reinterpret_cast<const i64x2*>(Bs + bO[kb] + n * 2048);
            xb0[n] = v.x; xb1[n] = v.y;
        }
    };
    auto mfmafrag = [&]() {
#pragma unroll
        for (int m = 0; m < 4; ++m)
#pragma unroll
            for (int n = 0; n < 4; ++n)
                acc[m][n] = __builtin_amdgcn_mfma_f32_16x16x32_fp8_fp8(
                    xa0[m], xb0[n], acc[m][n], 0, 0, 0);
#pragma unroll
        for (int m = 0; m < 4; ++m)
#pragma unroll
            for (int n = 0; n < 4; ++n)
                acc[m][n] = __builtin_amdgcn_mfma_f32_16x16x32_fp8_fp8(
                    xa1[m], xb1[n], acc[m][n], 0, 0, 0);
    };

    // Stage one 16KB-per-operand K-step: 8 loads/thread, imm offset T*128.
#define STAGE(T)                                                              \
    do {                                                                      \
        _Pragma("unroll")                                                     \
        for (int i = 0; i < 4; ++i) {                                         \
            __builtin_amdgcn_global_load_lds(                                 \
                (const __attribute__((address_space(1))) void*)aP[i],         \
                (__attribute__((address_space(3))) void*)                     \
                    ((char*)As + i * 4096 + wave * 1024), 16, (T) * 128, 0);  \
            __builtin_amdgcn_global_load_lds(                                 \
                (const __attribute__((address_space(1))) void*)bP[i],         \
                (__attribute__((address_space(3))) void*)                     \
                    ((char*)Bs + i * 4096 + wave * 1024), 16, (T) * 128, 0);  \
        }                                                                     \
    } while (0)

    STAGE(0);
    __syncthreads();          // prologue drain: step-0 tile ready

    // ---- step 0 (with step-1 prefetch) ----
    readfrag(0); mfmafrag();  // kb0
    readfrag(1);              // kb1 frags in regs BEFORE overwrite
    __syncthreads();          // (a) all waves' reads complete (lgkm drained)
    STAGE(1);                 // overwrite single buffer
    mfmafrag();               // kb1 (register-only, overlaps stage latency)
    __syncthreads();          // (b) vmcnt(0) drain: step-1 tile ready

    // ---- step 1 (no prefetch, no barriers) ----
    readfrag(0); mfmafrag();
    readfrag(1); mfmafrag();
#undef STAGE

    // ---- epilogue (R20-exact): logits*30, exp(logit-30) row-sums, label ----
    // C frag layout: col = lane&15, row = (lane>>4)*4 + reg (dtype-indep).
    // 220 zero-pad cols add ~0.4% to S -> loss bias ~4e-3 << 0.22.
#pragma unroll
    for (int m = 0; m < 4; ++m) {
#pragma unroll
        for (int reg = 0; reg < 4; ++reg) {
            int lrow = wm + m * 16 + (lane >> 4) * 4 + reg;
            int grow = row0 + lrow;
            int lab  = lbl[lrow];
            float s = 0.0f;
#pragma unroll
            for (int n = 0; n < 4; ++n) {
                int gcol = col0 + wn + n * 16 + (lane & 15);
                float logit = acc[m][n][reg] * 30.0f;
                s += __expf(logit - 30.0f);
                if (gcol == lab) labelLogit[grow] = logit;  // unique writer
            }
#pragma unroll
            for (int off = 1; off < 16; off <<= 1) s += __shfl_xor(s, off, 64);
            if ((lane & 15) == 0) rs[lrow][wave & 1] = s;
        }
    }
    __syncthreads();
    if (tid < BM)
        partial[(size_t)ct * N_ROWS + row0 + tid] = rs[tid][0] + rs[tid][1];
}

// Per-row nll + per-block partial sums (fixed order -> deterministic).
__global__ __launch_bounds__(256) void oim_rownll(
    const float* __restrict__ partial, const float* __restrict__ labelLogit,
    const int* __restrict__ roi, float* __restrict__ blksum)
{
    __shared__ float s1[256], s2[256];
    int tid = threadIdx.x;
    int r = blockIdx.x * 256 + tid;
    float S = 0.0f;
    for (int t = 0; t < CT; ++t) S += partial[(size_t)t * N_ROWS + r];
    float lse = 30.0f + logf(S);
    int lab = roi[r] - 1;
    bool valid = (lab != IGN);
    s1[tid] = valid ? (lse - labelLogit[r]) : 0.0f;
    s2[tid] = valid ? 1.0f : 0.0f;
    __syncthreads();
    for (int o = 128; o > 0; o >>= 1) {
        if (tid < o) { s1[tid] += s1[tid + o]; s2[tid] += s2[tid + o]; }
        __syncthreads();
    }
    if (tid == 0) {
        blksum[blockIdx.x]      = s1[0];
        blksum[32 + blockIdx.x] = s2[0];
    }
}

// Final: one wave reduces the 32 block sums.
__global__ __launch_bounds__(64) void oim_reduce(
    const float* __restrict__ blksum, float* __restrict__ out)
{
    int tid = threadIdx.x;
    float a = (tid < 32) ? blksum[tid]      : 0.0f;
    float b = (tid < 32) ? blksum[32 + tid] : 0.0f;
#pragma unroll
    for (int off = 32; off > 0; off >>= 1) {
        a += __shfl_xor(a, off, 64);
        b += __shfl_xor(b, off, 64);
    }
    if (tid == 0) out[0] = a / fmaxf(b, 1.0f);
}

extern "C" void kernel_launch(void* const* d_in, const int* in_sizes, int n_in,
                              void* d_out, int out_size, void* d_ws, size_t ws_size,
                              hipStream_t stream)
{
    const float* X   = (const float*)d_in[0];
    const int*   roi = (const int*)  d_in[1];
    const float* lut = (const float*)d_in[2];
    const float* cq  = (const float*)d_in[3];
    float* out = (float*)d_out;

    char* ws = (char*)d_ws;
    unsigned char* Xb = (unsigned char*)ws;                  // 8192*256 fp8
    unsigned char* Wb = Xb + (size_t)N_ROWS * K_DIM;         // 10752*256 fp8
    float* partial    = (float*)(Wb + (size_t)NCPAD * K_DIM);// 84*8192 f32
    float* labelLogit = partial + (size_t)CT * N_ROWS;       // 8192
    float* blksum     = labelLogit + N_ROWS;                 // 64
    size_t need = (size_t)N_ROWS * K_DIM + (size_t)NCPAD * K_DIM
                + (size_t)CT * N_ROWS * 4 + (size_t)(N_ROWS + 64) * 4;
    if (ws_size < need) return;   // refuse to run rather than corrupt memory

    const int TOT_CHUNKS = ((N_ROWS + NCPAD) * K_DIM) / 8;   // 606208
    oim_convert<<<(TOT_CHUNKS + 255) / 256, 256, 0, stream>>>(X, lut, cq, Xb, Wb);
    oim_gemm<<<NBLK, 256, 0, stream>>>(Xb, Wb, roi, partial, labelLogit);
    oim_rownll<<<N_ROWS / 256, 256, 0, stream>>>(partial, labelLogit, roi, blksum);
    oim_reduce<<<1, 64, 0, stream>>>(blksum, out);
}